// Round 8
// baseline (365.343 us; speedup 1.0000x reference)
//
#include <hip/hip_runtime.h>
#include <math.h>

#define NEG_SLOPE 0.2f

typedef short v8s __attribute__((ext_vector_type(8)));   // 8 bf16 in 4 VGPRs
typedef float v4f __attribute__((ext_vector_type(4)));

__device__ inline unsigned short f2bf(float x) {
  unsigned u = __float_as_uint(x);
  u += 0x7fffu + ((u >> 16) & 1u);  // RNE
  return (unsigned short)(u >> 16);
}

// ---------------- CSR build ----------------

__global__ void k_zero2(int* __restrict__ counts, int n, int* __restrict__ total) {
  int i = blockIdx.x * 256 + threadIdx.x;
  if (i < n) counts[i] = 0;
  if (i == 0) *total = 0;
}

__global__ void k_count(const int* __restrict__ dst, int* __restrict__ counts, int E) {
  int i = blockIdx.x * 256 + threadIdx.x;
  if (i < E) atomicAdd(&counts[dst[i]], 1);
}

__global__ void k_offsets(const int* __restrict__ counts, int* __restrict__ offsets,
                          int* __restrict__ cursor, int* __restrict__ total, int n) {
  int i = blockIdx.x * 256 + threadIdx.x;
  if (i < n) {
    int c = counts[i];
    int o = atomicAdd(total, c);
    offsets[i] = o;
    cursor[i] = o;
  }
}

__global__ void k_fill(const int* __restrict__ src, const int* __restrict__ dst,
                       int* __restrict__ cursor, int* __restrict__ csr_src, int E) {
  int i = blockIdx.x * 256 + threadIdx.x;
  if (i < E) {
    int d = dst[i];
    int pos = atomicAdd(&cursor[d], 1);
    csr_src[pos] = src[i];
  }
}

// ---------------- prep: W1 -> transposed bf16 ----------------

__global__ void k_prepW(const float* __restrict__ W1, unsigned short* __restrict__ W1T) {
  int gid = blockIdx.x * 256 + threadIdx.x;
  if (gid < 32768) {
    int k = gid & 127, nn = gid >> 7;
    W1T[nn * 128 + k] = f2bf(W1[k * 256 + nn]);
  }
}

// ---------------- Layer 1 MFMA GEMM (fp32 x staged->bf16, all 256 cols per block) + fused el/er ----------------
__global__ __launch_bounds__(256) void k_gemm1(const float* __restrict__ x,
                                               const unsigned short* __restrict__ W1T,
                                               const float* __restrict__ al,
                                               const float* __restrict__ ar,
                                               unsigned short* __restrict__ f1b,
                                               float* __restrict__ el,
                                               float* __restrict__ er, int n) {
  __shared__ __align__(16) unsigned short xs[64][136];
  __shared__ __align__(16) unsigned short ws[64][136];
  const int tid = threadIdx.x;
  const int m0 = blockIdx.x * 64;

#pragma unroll
  for (int r = 0; r < 8; ++r) {
    int idx = r * 256 + tid;
    int m = idx >> 5, c4 = idx & 31;
    int gn = m0 + m;
    float4 v = make_float4(0.f, 0.f, 0.f, 0.f);
    if (gn < n) v = *(const float4*)(x + (size_t)gn * 128 + c4 * 4);
    ushort4 pk;
    pk.x = f2bf(v.x); pk.y = f2bf(v.y); pk.z = f2bf(v.z); pk.w = f2bf(v.w);
    *(ushort4*)(&xs[m][c4 * 4]) = pk;
  }

  const int wave = tid >> 6, lane = tid & 63;
  const int quad = lane >> 4, col16 = lane & 15;

  for (int cb = 0; cb < 4; ++cb) {
    const int c0 = cb * 64;
#pragma unroll
    for (int r = 0; r < 4; ++r) {
      int idx = r * 256 + tid;
      int m = idx >> 4, kc = idx & 15;
      const ushort4* q = (const ushort4*)(W1T + (size_t)(c0 + m) * 128 + kc * 8);
      *(ushort4*)(&ws[m][kc * 8]) = q[0];
      *(ushort4*)(&ws[m][kc * 8 + 4]) = q[1];
    }
    __syncthreads();

    v4f acc[4];
#pragma unroll
    for (int nt = 0; nt < 4; ++nt) acc[nt] = (v4f){0.f, 0.f, 0.f, 0.f};

#pragma unroll
    for (int kc = 0; kc < 4; ++kc) {
      v8s a = *(const v8s*)(&xs[wave * 16 + col16][kc * 32 + quad * 8]);
#pragma unroll
      for (int nt = 0; nt < 4; ++nt) {
        v8s b = *(const v8s*)(&ws[nt * 16 + col16][kc * 32 + quad * 8]);
        acc[nt] = __builtin_amdgcn_mfma_f32_16x16x32_bf16(a, b, acc[nt], 0, 0, 0);
      }
    }

    float pel[4][2], per_r[4][2];
#pragma unroll
    for (int rg = 0; rg < 4; ++rg) {
      pel[rg][0] = pel[rg][1] = 0.f;
      per_r[rg][0] = per_r[rg][1] = 0.f;
    }
#pragma unroll
    for (int nt = 0; nt < 4; ++nt) {
      int gcol = c0 + nt * 16 + col16;
      float alv = al[gcol], arv = ar[gcol];
      int hh = nt >> 1;
#pragma unroll
      for (int rg = 0; rg < 4; ++rg) {
        int gn = m0 + wave * 16 + quad * 4 + rg;
        float v = acc[nt][rg];
        if (gn < n) f1b[(size_t)gn * 256 + gcol] = f2bf(v);
        pel[rg][hh] += v * alv;
        per_r[rg][hh] += v * arv;
      }
    }
#pragma unroll
    for (int off = 1; off < 16; off <<= 1) {
#pragma unroll
      for (int rg = 0; rg < 4; ++rg) {
#pragma unroll
        for (int hh = 0; hh < 2; ++hh) {
          pel[rg][hh] += __shfl_xor(pel[rg][hh], off, 64);
          per_r[rg][hh] += __shfl_xor(per_r[rg][hh], off, 64);
        }
      }
    }
    if (col16 == 0) {
      int hb = cb * 2;
#pragma unroll
      for (int rg = 0; rg < 4; ++rg) {
        int gn = m0 + wave * 16 + quad * 4 + rg;
        if (gn < n) {
#pragma unroll
          for (int hh = 0; hh < 2; ++hh) {
            el[gn * 8 + hb + hh] = pel[rg][hh];
            er[gn * 8 + hb + hh] = per_r[rg][hh];
          }
        }
      }
    }
    __syncthreads();
  }
}

// ---------------- Layer 1 aggregation + fused layer-2 GEMM ----------------
// block per node. Phase A (per 256-edge chunk): thread j computes 8 head-weights once -> LDS.
// Phase B: halfwave-per-edge bf16 gather, weights from LDS.
// Epilogue: h in LDS -> matvec with W2 (fp32, L1-hot) -> f2b + el2/er2. No h materialization.
__global__ __launch_bounds__(256) void k_agg1(const unsigned short* __restrict__ f1b,
                                              const float* __restrict__ el,
                                              const float* __restrict__ er,
                                              const int* __restrict__ offsets,
                                              const int* __restrict__ counts,
                                              const int* __restrict__ csr_src,
                                              const float* __restrict__ b1,
                                              const float* __restrict__ W2,
                                              const float* __restrict__ al2,
                                              const float* __restrict__ ar2,
                                              unsigned short* __restrict__ f2b,
                                              float* __restrict__ el2,
                                              float* __restrict__ er2, int n) {
  const int node = blockIdx.x;
  const int tid = threadIdx.x;
  const int hw = tid >> 5, lane32 = tid & 31;
  const int hd = lane32 >> 2;
  __shared__ __align__(16) float s_w[256][8];    // 8KB: per-edge per-head weights
  __shared__ __align__(16) float s_acc[8][260];  // halfwave partial sums
  __shared__ float s_dw[8][32];
  __shared__ float s_h[256];
  __shared__ float s_part[8][33];

  const int start = offsets[node], deg = counts[node];

  // all 8 er values for this node (broadcast loads)
  float er_a[8];
  {
    float4 r0 = *(const float4*)(er + (size_t)node * 8);
    float4 r1 = *(const float4*)(er + (size_t)node * 8 + 4);
    er_a[0] = r0.x; er_a[1] = r0.y; er_a[2] = r0.z; er_a[3] = r0.w;
    er_a[4] = r1.x; er_a[5] = r1.y; er_a[6] = r1.z; er_a[7] = r1.w;
  }

  float a[8];
#pragma unroll
  for (int d = 0; d < 8; ++d) a[d] = 0.f;
  float dw = 0.f;

  const unsigned short* fbase = f1b + lane32 * 8;

  for (int c0 = 0; c0 < deg; c0 += 256) {
    const int cn = min(256, deg - c0);
    // phase A: one thread per edge computes 8 head weights
    if (tid < cn) {
      int s = csr_src[start + c0 + tid];
      float4 e0 = *(const float4*)(el + (size_t)s * 8);
      float4 e1 = *(const float4*)(el + (size_t)s * 8 + 4);
      float ev[8] = {e0.x, e0.y, e0.z, e0.w, e1.x, e1.y, e1.z, e1.w};
#pragma unroll
      for (int h = 0; h < 8; ++h) {
        float v = ev[h] + er_a[h];
        v = (v >= 0.f) ? v : NEG_SLOPE * v;
        s_w[tid][h] = __expf(v);
      }
    }
    __syncthreads();

    // phase B: gather, 2 edges per wave in flight
    int j0 = hw;
    int s0 = (j0 < cn) ? csr_src[start + c0 + j0] : -1;
    int s1 = (j0 + 8 < cn) ? csr_src[start + c0 + j0 + 8] : -1;
    while (j0 < cn) {
      int jn = j0 + 16;
      int sn0 = (jn < cn) ? csr_src[start + c0 + jn] : -1;
      int sn1 = (jn + 8 < cn) ? csr_src[start + c0 + jn + 8] : -1;
      uint4 vb0 = *(const uint4*)(fbase + (size_t)s0 * 256);
      float w0 = s_w[j0][hd];
      uint4 vb1 = make_uint4(0, 0, 0, 0);
      float w1 = 0.f;
      bool has1 = (s1 >= 0);
      if (has1) {
        vb1 = *(const uint4*)(fbase + (size_t)s1 * 256);
        w1 = s_w[j0 + 8][hd];
      }
      a[0] += w0 * __uint_as_float(vb0.x << 16);
      a[1] += w0 * __uint_as_float(vb0.x & 0xffff0000u);
      a[2] += w0 * __uint_as_float(vb0.y << 16);
      a[3] += w0 * __uint_as_float(vb0.y & 0xffff0000u);
      a[4] += w0 * __uint_as_float(vb0.z << 16);
      a[5] += w0 * __uint_as_float(vb0.z & 0xffff0000u);
      a[6] += w0 * __uint_as_float(vb0.w << 16);
      a[7] += w0 * __uint_as_float(vb0.w & 0xffff0000u);
      dw += w0;
      if (has1) {
        a[0] += w1 * __uint_as_float(vb1.x << 16);
        a[1] += w1 * __uint_as_float(vb1.x & 0xffff0000u);
        a[2] += w1 * __uint_as_float(vb1.y << 16);
        a[3] += w1 * __uint_as_float(vb1.y & 0xffff0000u);
        a[4] += w1 * __uint_as_float(vb1.z << 16);
        a[5] += w1 * __uint_as_float(vb1.z & 0xffff0000u);
        a[6] += w1 * __uint_as_float(vb1.w << 16);
        a[7] += w1 * __uint_as_float(vb1.w & 0xffff0000u);
        dw += w1;
      }
      s0 = sn0; s1 = sn1; j0 = jn;
    }
    __syncthreads();  // protect s_w before next chunk
  }

  *(float4*)(&s_acc[hw][lane32 * 8])     = make_float4(a[0], a[1], a[2], a[3]);
  *(float4*)(&s_acc[hw][lane32 * 8 + 4]) = make_float4(a[4], a[5], a[6], a[7]);
  s_dw[hw][lane32] = dw;
  __syncthreads();

  // h epilogue -> LDS only
  {
    int t = tid;
    float sum = 0.f;
#pragma unroll
    for (int g = 0; g < 8; ++g) sum += s_acc[g][t];
    int hh = t >> 5;
    float denom = 0.f;
#pragma unroll
    for (int g = 0; g < 8; ++g) denom += s_dw[g][hh * 4];
    float inv = (deg > 0) ? 1.f / denom : 0.f;
    float o = sum * inv + b1[t];
    o = (o > 0.f) ? o : (__expf(o) - 1.f);
    s_h[t] = o;
  }
  __syncthreads();

  // fused layer-2 matvec: f2[c] = sum_t h[t] * W2[t][c]
  {
    int g = tid >> 5, c = tid & 31;
    float acc2 = 0.f;
#pragma unroll 8
    for (int t8 = 0; t8 < 32; ++t8) {
      int t = g * 32 + t8;
      acc2 += s_h[t] * W2[t * 32 + c];
    }
    s_part[g][c] = acc2;
  }
  __syncthreads();
  if (tid < 32) {
    int c = tid;
    float f2 = 0.f;
#pragma unroll
    for (int g = 0; g < 8; ++g) f2 += s_part[g][c];
    f2b[(size_t)node * 32 + c] = f2bf(f2);
    float pe = f2 * al2[c], pr = f2 * ar2[c];
#pragma unroll
    for (int off = 1; off < 32; off <<= 1) {
      pe += __shfl_xor(pe, off, 64);
      pr += __shfl_xor(pr, off, 64);
    }
    if (c == 0) { el2[node] = pe; er2[node] = pr; }
  }
}

// ---------------- Layer 2 aggregation: bf16 f2, 16-lane edge groups, unroll x2 ----------------
__global__ __launch_bounds__(256) void k_agg2(const unsigned short* __restrict__ f2b,
                                              const float* __restrict__ el2,
                                              const float* __restrict__ er2,
                                              const int* __restrict__ offsets,
                                              const int* __restrict__ counts,
                                              const int* __restrict__ csr_src,
                                              const float* __restrict__ b2,
                                              float* __restrict__ out, int n) {
  int wid = threadIdx.x >> 6, lane = threadIdx.x & 63;
  int node = blockIdx.x * 4 + wid;
  if (node >= n) return;
  int eg = lane >> 4, l16 = lane & 15;
  int start = offsets[node], deg = counts[node];
  float er0 = er2[node];
  float a0 = 0.f, a1 = 0.f, dw = 0.f;

  const unsigned short* fbase = f2b + l16 * 2;

  int j = eg;
  int s0 = (j < deg) ? csr_src[start + j] : -1;
  int s1 = (j + 4 < deg) ? csr_src[start + j + 4] : -1;
  while (j < deg) {
    int jn = j + 8;
    int sn0 = (jn < deg) ? csr_src[start + jn] : -1;
    int sn1 = (jn + 4 < deg) ? csr_src[start + jn + 4] : -1;
    unsigned vb0 = *(const unsigned*)(fbase + (size_t)s0 * 32);
    float e0 = el2[s0];
    unsigned vb1 = 0; float e1 = 0.f;
    bool has1 = (s1 >= 0);
    if (has1) {
      vb1 = *(const unsigned*)(fbase + (size_t)s1 * 32);
      e1 = el2[s1];
    }
    {
      float ev = e0 + er0;
      ev = (ev >= 0.f) ? ev : NEG_SLOPE * ev;
      float w = __expf(ev);
      a0 += w * __uint_as_float(vb0 << 16);
      a1 += w * __uint_as_float(vb0 & 0xffff0000u);
      dw += w;
    }
    if (has1) {
      float ev = e1 + er0;
      ev = (ev >= 0.f) ? ev : NEG_SLOPE * ev;
      float w = __expf(ev);
      a0 += w * __uint_as_float(vb1 << 16);
      a1 += w * __uint_as_float(vb1 & 0xffff0000u);
      dw += w;
    }
    s0 = sn0; s1 = sn1; j = jn;
  }
#pragma unroll
  for (int off = 16; off <= 32; off <<= 1) {
    a0 += __shfl_xor(a0, off, 64);
    a1 += __shfl_xor(a1, off, 64);
    dw += __shfl_xor(dw, off, 64);
  }
  if (eg == 0) {
    float inv = (deg > 0) ? 1.f / dw : 0.f;
    float2 r;
    r.x = a0 * inv + b2[l16 * 2];
    r.y = a1 * inv + b2[l16 * 2 + 1];
    *(float2*)(out + (size_t)node * 32 + l16 * 2) = r;
  }
}

// ---------------- launch ----------------

extern "C" void kernel_launch(void* const* d_in, const int* in_sizes, int n_in,
                              void* d_out, int out_size, void* d_ws, size_t ws_size,
                              hipStream_t stream) {
  const float* x   = (const float*)d_in[0];
  const int*   src = (const int*)d_in[1];
  const int*   dst = (const int*)d_in[2];
  const float* W1  = (const float*)d_in[3];
  const float* al1 = (const float*)d_in[4];
  const float* ar1 = (const float*)d_in[5];
  const float* b1  = (const float*)d_in[6];
  const float* W2  = (const float*)d_in[7];
  const float* al2 = (const float*)d_in[8];
  const float* ar2 = (const float*)d_in[9];
  const float* b2  = (const float*)d_in[10];
  float* out = (float*)d_out;

  int N = in_sizes[0] / 128;
  int E = in_sizes[1];

  char* w = (char*)d_ws;
  auto alloc = [&](size_t nbytes) -> void* {
    void* p = (void*)w;
    w += ((nbytes + 255) / 256) * 256;
    return p;
  };
  unsigned short* W1T = (unsigned short*)alloc(256 * 128 * 2);
  unsigned short* f1b = (unsigned short*)alloc((size_t)N * 256 * 2);
  unsigned short* f2b = (unsigned short*)alloc((size_t)N * 32 * 2);
  float* el1  = (float*)alloc((size_t)N * 8 * 4);
  float* er1  = (float*)alloc((size_t)N * 8 * 4);
  float* el2  = (float*)alloc((size_t)N * 4);
  float* er2  = (float*)alloc((size_t)N * 4);
  int* counts  = (int*)alloc((size_t)N * 4);
  int* offsets = (int*)alloc((size_t)N * 4);
  int* cursor  = (int*)alloc((size_t)N * 4);
  int* total   = (int*)alloc(4);
  int* csr_src = (int*)alloc((size_t)E * 4);

  hipLaunchKernelGGL(k_zero2, dim3((N + 255) / 256), dim3(256), 0, stream, counts, N, total);
  hipLaunchKernelGGL(k_count, dim3((E + 255) / 256), dim3(256), 0, stream, dst, counts, E);
  hipLaunchKernelGGL(k_offsets, dim3((N + 255) / 256), dim3(256), 0, stream, counts, offsets, cursor, total, N);
  hipLaunchKernelGGL(k_fill, dim3((E + 255) / 256), dim3(256), 0, stream, src, dst, cursor, csr_src, E);
  hipLaunchKernelGGL(k_prepW, dim3(128), dim3(256), 0, stream, W1, W1T);
  hipLaunchKernelGGL(k_gemm1, dim3((N + 63) / 64), dim3(256), 0, stream, x, W1T, al1, ar1, f1b, el1, er1, N);
  hipLaunchKernelGGL(k_agg1, dim3(N), dim3(256), 0, stream, f1b, el1, er1, offsets, counts, csr_src, b1,
                     W2, al2, ar2, f2b, el2, er2, N);
  hipLaunchKernelGGL(k_agg2, dim3((N + 3) / 4), dim3(256), 0, stream, f2b, el2, er2, offsets, counts, csr_src,
                     b2, out, N);
}